// Round 2
// baseline (272.096 us; speedup 1.0000x reference)
//
#include <hip/hip_runtime.h>
#include <math.h>

#define B_ 2
#define T_ 2048
#define C_ 1024
#define H_ 16
#define D_ 64
#define M_ (B_*T_)

typedef unsigned short u16;
typedef __attribute__((ext_vector_type(8))) short short8;
typedef __attribute__((ext_vector_type(4))) float f32x4;

__device__ inline u16 f2bf(float f){
  union { float f; unsigned u; } v; v.f = f;
  unsigned r = (v.u + 0x7FFF + ((v.u >> 16) & 1)) >> 16;
  return (u16)r;
}

__device__ inline void gload_lds16(const void* g, void* l){
  __builtin_amdgcn_global_load_lds(
      (const __attribute__((address_space(1))) unsigned*)g,
      (__attribute__((address_space(3))) unsigned*)l, 16, 0, 0);
}

// ---------------- x -> bf16 ----------------
__global__ void k_cvt_x(const float* __restrict__ x, u16* __restrict__ xb){
  int i = (blockIdx.x * 256 + threadIdx.x) * 8;
  float4 a = *(const float4*)(x + i);
  float4 b = *(const float4*)(x + i + 4);
  short8 o;
  o[0] = (short)f2bf(a.x); o[1] = (short)f2bf(a.y);
  o[2] = (short)f2bf(a.z); o[3] = (short)f2bf(a.w);
  o[4] = (short)f2bf(b.x); o[5] = (short)f2bf(b.y);
  o[6] = (short)f2bf(b.z); o[7] = (short)f2bf(b.w);
  *(short8*)(xb + i) = o;
}

// ---------------- W [K][N] fp32 -> Wt [N][K] bf16 ----------------
__global__ void k_transW(const float* __restrict__ W, u16* __restrict__ Wt, int K, int N){
  __shared__ float t[32][33];
  int bn = blockIdx.x * 32, bk = blockIdx.y * 32;
  int tx = threadIdx.x, ty = threadIdx.y; // (32,8)
  #pragma unroll
  for (int i = 0; i < 32; i += 8)
    t[ty + i][tx] = W[(size_t)(bk + ty + i) * N + bn + tx];
  __syncthreads();
  #pragma unroll
  for (int i = 0; i < 32; i += 8)
    Wt[(size_t)(bn + ty + i) * K + bk + tx] = f2bf(t[tx][ty + i]);
}

// ---------------- v [bh][T][D] -> vt [bh][D][T] (bf16) ----------------
__global__ void k_transV(const u16* __restrict__ v, u16* __restrict__ vt){
  __shared__ u16 t[32][33];
  int bh = blockIdx.z;
  int t0 = blockIdx.x * 32, d0 = blockIdx.y * 32;
  int tx = threadIdx.x, ty = threadIdx.y;
  const u16* vs = v + (size_t)bh * T_ * D_;
  u16* vd = vt + (size_t)bh * T_ * D_;
  #pragma unroll
  for (int i = 0; i < 32; i += 8)
    t[ty + i][tx] = vs[(size_t)(t0 + ty + i) * D_ + d0 + tx];
  __syncthreads();
  #pragma unroll
  for (int i = 0; i < 32; i += 8)
    vd[(size_t)(d0 + ty + i) * T_ + t0 + tx] = t[tx][ty + i];
}

// ---------------- 128x128 GEMM, A[M][K] * Bt[N][K]^T, bf16 MFMA ----------------
// EPI 0: scatter q/k/v bf16 per-head.  EPI 1: fp32 out + bias.
template<int EPI>
__launch_bounds__(256, 2)
__global__ void k_gemm(const u16* __restrict__ A, const u16* __restrict__ Bt,
                       const float* __restrict__ bias, float* __restrict__ outF,
                       u16* __restrict__ oq, u16* __restrict__ ok, u16* __restrict__ ov,
                       int M, int N, int K){
  __shared__ u16 lA[128 * 32];
  __shared__ u16 lB[128 * 32];
  int tid = threadIdx.x, lane = tid & 63, wv = tid >> 6;
  int bm = blockIdx.y * 128, bn = blockIdx.x * 128;
  int wr = (wv >> 1) * 64, wc = (wv & 1) * 64;
  f32x4 acc[4][4] = {};

  const u16* Ab = A + (size_t)(bm + wv * 32 + (lane >> 2)) * K + (lane & 3) * 8;
  const u16* Bb = Bt + (size_t)(bn + wv * 32 + (lane >> 2)) * K + (lane & 3) * 8;
  u16* lAd = &lA[wv * 1024];
  u16* lBd = &lB[wv * 1024];
  int ar = wr + (lane & 15);
  int br = wc + (lane & 15);
  int kc = (lane >> 4) * 8;

  for (int k0 = 0; k0 < K; k0 += 32){
    gload_lds16(Ab + k0, lAd);
    gload_lds16(Ab + k0 + (size_t)16 * K, lAd + 512);
    gload_lds16(Bb + k0, lBd);
    gload_lds16(Bb + k0 + (size_t)16 * K, lBd + 512);
    __syncthreads();
    short8 afr[4], bfr[4];
    #pragma unroll
    for (int m = 0; m < 4; m++) afr[m] = *(const short8*)&lA[(ar + m * 16) * 32 + kc];
    #pragma unroll
    for (int n = 0; n < 4; n++) bfr[n] = *(const short8*)&lB[(br + n * 16) * 32 + kc];
    #pragma unroll
    for (int m = 0; m < 4; m++)
      #pragma unroll
      for (int n = 0; n < 4; n++)
        acc[m][n] = __builtin_amdgcn_mfma_f32_16x16x32_bf16(afr[m], bfr[n], acc[m][n], 0, 0, 0);
    __syncthreads();
  }

  if (EPI == 1){
    #pragma unroll
    for (int m = 0; m < 4; m++){
      int gmB = bm + wr + m * 16 + ((lane >> 4) << 2);
      #pragma unroll
      for (int n = 0; n < 4; n++){
        int gn = bn + wc + n * 16 + (lane & 15);
        float bia = bias[gn];
        #pragma unroll
        for (int j = 0; j < 4; j++)
          outF[(size_t)(gmB + j) * N + gn] = acc[m][n][j] + bia;
      }
    }
  } else {
    #pragma unroll
    for (int m = 0; m < 4; m++){
      int gmB = bm + wr + m * 16 + ((lane >> 4) << 2);
      #pragma unroll
      for (int n = 0; n < 4; n++){
        int gn = bn + wc + n * 16 + (lane & 15);
        float bia = bias[gn];
        int part = gn >> 10;
        int col = gn & 1023;
        int h = col >> 6, d = col & 63;
        u16* dst = (part == 0) ? oq : (part == 1) ? ok : ov;
        #pragma unroll
        for (int j = 0; j < 4; j++){
          int gm = gmB + j;
          int b = gm >> 11, t = gm & 2047;
          dst[((size_t)(b * H_ + h) * T_ + t) * D_ + d] = f2bf(acc[m][n][j] + bia);
        }
      }
    }
  }
}

// ---------------- flash attention ----------------
// q,k: [bh][T][D] bf16; vt: [bh][D][T] bf16; y: [b][t][C] bf16 (head-major cols)
__launch_bounds__(256, 2)
__global__ void k_attn(const u16* __restrict__ q, const u16* __restrict__ k,
                       const u16* __restrict__ vt, u16* __restrict__ y,
                       const float* __restrict__ tempPtr){
  __shared__ u16 lK[64 * 72];
  __shared__ u16 lV[64 * 72];
  __shared__ u16 lP[4][32 * 72];
  int tid = threadIdx.x, lane = tid & 63, wv = tid >> 6;
  int bh = blockIdx.x;
  int h = bh & (H_ - 1);
  int yy = blockIdx.y;                       // work-balance remap for causal
  int qt = (yy & 1) ? ((yy - 1) >> 1) : (15 - (yy >> 1));
  int q0 = qt * 128;
  float scl = 1.0f / (8.0f * tempPtr[0]);
  float slope = exp2f(-0.5f * (float)(h + 1));
  const u16* qp = q + (size_t)bh * T_ * D_;
  const u16* kp = k + (size_t)bh * T_ * D_;
  const u16* vp = vt + (size_t)bh * T_ * D_;

  // Q fragments in registers for the whole KV loop
  short8 aq[2][2];
  int qrow = q0 + wv * 32 + (lane & 15);
  int kc = (lane >> 4) * 8;
  #pragma unroll
  for (int m = 0; m < 2; m++)
    #pragma unroll
    for (int ks = 0; ks < 2; ks++)
      aq[m][ks] = *(const short8*)&qp[(size_t)(qrow + m * 16) * D_ + ks * 32 + kc];

  float mrun[2][4], lrun[2][4];
  f32x4 acco[2][4] = {};
  #pragma unroll
  for (int m = 0; m < 2; m++)
    #pragma unroll
    for (int j = 0; j < 4; j++){ mrun[m][j] = -1e30f; lrun[m][j] = 0.f; }

  int ntiles = (q0 + 128) >> 6;
  int wqmax = q0 + wv * 32 + 31;
  int sr = tid >> 2, scol = (tid & 3) * 16;

  for (int it = 0; it < ntiles; it++){
    int kv0 = it * 64;
    { // stage K tile [kv][d] and V^T tile [d][kv]
      const u16* gk = &kp[(size_t)(kv0 + sr) * D_ + scol];
      *(short8*)&lK[sr * 72 + scol]     = *(const short8*)gk;
      *(short8*)&lK[sr * 72 + scol + 8] = *(const short8*)(gk + 8);
      const u16* gv = &vp[(size_t)sr * T_ + kv0 + scol];
      *(short8*)&lV[sr * 72 + scol]     = *(const short8*)gv;
      *(short8*)&lV[sr * 72 + scol + 8] = *(const short8*)(gv + 8);
    }
    __syncthreads();
    if (kv0 <= wqmax){
      // S = Q * K^T
      f32x4 accs[2][4] = {};
      #pragma unroll
      for (int ks = 0; ks < 2; ks++){
        short8 bk[4];
        #pragma unroll
        for (int n = 0; n < 4; n++)
          bk[n] = *(const short8*)&lK[(n * 16 + (lane & 15)) * 72 + ks * 32 + kc];
        #pragma unroll
        for (int m = 0; m < 2; m++)
          #pragma unroll
          for (int n = 0; n < 4; n++)
            accs[m][n] = __builtin_amdgcn_mfma_f32_16x16x32_bf16(aq[m][ks], bk[n], accs[m][n], 0, 0, 0);
      }
      // online softmax with ALiBi + causal
      int kvb = kv0 + (lane & 15);
      #pragma unroll
      for (int m = 0; m < 2; m++){
        float pvv[4][4];   // [n][j]
        float alpha[4];
        #pragma unroll
        for (int j = 0; j < 4; j++){
          int qi = q0 + wv * 32 + m * 16 + ((lane >> 4) << 2) + j;
          float mx = -1e30f;
          #pragma unroll
          for (int n = 0; n < 4; n++){
            int kvi = kvb + n * 16;
            float s = accs[m][n][j] * scl + slope * (float)(kvi - qi);
            s = (kvi <= qi) ? s : -1e30f;
            pvv[n][j] = s;
            mx = fmaxf(mx, s);
          }
          mx = fmaxf(mx, __shfl_xor(mx, 1));
          mx = fmaxf(mx, __shfl_xor(mx, 2));
          mx = fmaxf(mx, __shfl_xor(mx, 4));
          mx = fmaxf(mx, __shfl_xor(mx, 8));
          float newm = fmaxf(mrun[m][j], mx);
          float al = __expf(mrun[m][j] - newm);
          float rs = 0.f;
          #pragma unroll
          for (int n = 0; n < 4; n++){
            float p = __expf(pvv[n][j] - newm);
            pvv[n][j] = p;
            rs += p;
          }
          rs += __shfl_xor(rs, 1);
          rs += __shfl_xor(rs, 2);
          rs += __shfl_xor(rs, 4);
          rs += __shfl_xor(rs, 8);
          lrun[m][j] = lrun[m][j] * al + rs;
          mrun[m][j] = newm;
          alpha[j] = al;
        }
        #pragma unroll
        for (int n = 0; n < 4; n++)
          #pragma unroll
          for (int j = 0; j < 4; j++){
            acco[m][n][j] *= alpha[j];
            lP[wv][(m * 16 + ((lane >> 4) << 2) + j) * 72 + n * 16 + (lane & 15)] = f2bf(pvv[n][j]);
          }
      }
      // O += P * V   (P re-read in A-frag layout from LDS)
      #pragma unroll
      for (int ks = 0; ks < 2; ks++){
        short8 pa[2], bv[4];
        #pragma unroll
        for (int m = 0; m < 2; m++)
          pa[m] = *(const short8*)&lP[wv][(m * 16 + (lane & 15)) * 72 + ks * 32 + kc];
        #pragma unroll
        for (int n = 0; n < 4; n++)
          bv[n] = *(const short8*)&lV[(n * 16 + (lane & 15)) * 72 + ks * 32 + kc];
        #pragma unroll
        for (int m = 0; m < 2; m++)
          #pragma unroll
          for (int n = 0; n < 4; n++)
            acco[m][n] = __builtin_amdgcn_mfma_f32_16x16x32_bf16(pa[m], bv[n], acco[m][n], 0, 0, 0);
      }
    }
    __syncthreads();
  }

  int b = bh >> 4;
  #pragma unroll
  for (int m = 0; m < 2; m++)
    #pragma unroll
    for (int j = 0; j < 4; j++){
      int t = q0 + wv * 32 + m * 16 + ((lane >> 4) << 2) + j;
      float inv = 1.0f / lrun[m][j];
      #pragma unroll
      for (int n = 0; n < 4; n++)
        y[(size_t)(b * T_ + t) * C_ + h * D_ + n * 16 + (lane & 15)] = f2bf(acco[m][n][j] * inv);
    }
}

// ---------------- launcher ----------------
// Workspace layout (40 MB peak, aliased by lifetime):
//   [0,  8)  xb   (x as bf16)        -- dead after k_gemm<0>
//   [0,  8)  vtw  (V^T)              -- overlays xb, written by k_transV
//   [8, 14)  wab  (W_attn^T bf16)    -- dead after k_gemm<0>
//   [14,16)  wpt  (W_proj^T bf16)    -- live until k_gemm<1>
//   [16,24)  qw   | [24,32) kw       -- live until k_attn
//   [32,40)  vw   (V)                -- dead after k_transV
//   [32,40)  yb   (attn out bf16)    -- overlays vw, written by k_attn
extern "C" void kernel_launch(void* const* d_in, const int* in_sizes, int n_in,
                              void* d_out, int out_size, void* d_ws, size_t ws_size,
                              hipStream_t stream){
  const float* x      = (const float*)d_in[0];
  const float* W_attn = (const float*)d_in[1];
  const float* b_attn = (const float*)d_in[2];
  const float* W_proj = (const float*)d_in[3];
  const float* b_proj = (const float*)d_in[4];
  const float* temp   = (const float*)d_in[5];
  float* out = (float*)d_out;

  if (ws_size < (size_t)41943040) return;  // need 40 MB scratch
  char* ws = (char*)d_ws;
  u16* xb  = (u16*)(ws);                    // 8 MB
  u16* wab = (u16*)(ws + 8388608);          // 6 MB
  u16* wpt = (u16*)(ws + 14680064);         // 2 MB
  u16* qw  = (u16*)(ws + 16777216);         // 8 MB
  u16* kw  = (u16*)(ws + 25165824);         // 8 MB
  u16* vw  = (u16*)(ws + 33554432);         // 8 MB
  u16* vtw = (u16*)(ws);                    // 8 MB (overlays xb)
  u16* yb  = (u16*)(ws + 33554432);         // 8 MB (overlays vw)

  k_cvt_x<<<2048, 256, 0, stream>>>(x, xb);
  k_transW<<<dim3(96, 32), dim3(32, 8), 0, stream>>>(W_attn, wab, 1024, 3072);
  k_transW<<<dim3(32, 32), dim3(32, 8), 0, stream>>>(W_proj, wpt, 1024, 1024);
  k_gemm<0><<<dim3(24, 32), 256, 0, stream>>>(xb, wab, b_attn, nullptr, qw, kw, vw,
                                              4096, 3072, 1024);
  k_transV<<<dim3(64, 2, 32), dim3(32, 8), 0, stream>>>(vw, vtw);
  k_attn<<<dim3(32, 16), 256, 0, stream>>>(qw, kw, vtw, yb, temp);
  k_gemm<1><<<dim3(8, 32), 256, 0, stream>>>(yb, wpt, b_proj, out, nullptr, nullptr, nullptr,
                                             4096, 1024, 1024);
}

// Round 3
// 231.608 us; speedup vs baseline: 1.1748x; 1.1748x over previous
//
#include <hip/hip_runtime.h>
#include <math.h>

#define B_ 2
#define T_ 2048
#define C_ 1024
#define H_ 16
#define D_ 64
#define M_ (B_*T_)

typedef unsigned short u16;
typedef unsigned int u32;
typedef __attribute__((ext_vector_type(8))) short short8;
typedef __attribute__((ext_vector_type(4))) float f32x4;

__device__ inline u16 f2bf(float f){
  union { float f; unsigned u; } v; v.f = f;
  unsigned r = (v.u + 0x7FFF + ((v.u >> 16) & 1)) >> 16;
  return (u16)r;
}

__device__ inline void gload_lds16(const void* g, void* l){
  __builtin_amdgcn_global_load_lds(
      (const __attribute__((address_space(1))) unsigned*)g,
      (__attribute__((address_space(3))) unsigned*)l, 16, 0, 0);
}

// byte offset into a [rows][64]u16 (128B-row) LDS tile with 16B-chunk XOR swizzle
__device__ inline int swzb(int row, int chunk){
  return (row << 7) | ((chunk ^ (row & 7)) << 4);
}

// ---------------- x -> bf16 ----------------
__global__ void k_cvt_x(const float* __restrict__ x, u16* __restrict__ xb){
  int i = (blockIdx.x * 256 + threadIdx.x) * 8;
  float4 a = *(const float4*)(x + i);
  float4 b = *(const float4*)(x + i + 4);
  short8 o;
  o[0] = (short)f2bf(a.x); o[1] = (short)f2bf(a.y);
  o[2] = (short)f2bf(a.z); o[3] = (short)f2bf(a.w);
  o[4] = (short)f2bf(b.x); o[5] = (short)f2bf(b.y);
  o[6] = (short)f2bf(b.z); o[7] = (short)f2bf(b.w);
  *(short8*)(xb + i) = o;
}

// ---------------- W [K][N] fp32 -> Wt [N][K] bf16 ----------------
__global__ void k_transW(const float* __restrict__ W, u16* __restrict__ Wt, int K, int N){
  __shared__ float t[32][33];
  int bn = blockIdx.x * 32, bk = blockIdx.y * 32;
  int tx = threadIdx.x, ty = threadIdx.y; // (32,8)
  #pragma unroll
  for (int i = 0; i < 32; i += 8)
    t[ty + i][tx] = W[(size_t)(bk + ty + i) * N + bn + tx];
  __syncthreads();
  #pragma unroll
  for (int i = 0; i < 32; i += 8)
    Wt[(size_t)(bn + ty + i) * K + bk + tx] = f2bf(t[tx][ty + i]);
}

// ---------------- v [bh][T][D] -> vt [bh][D][T] (bf16) ----------------
__global__ void k_transV(const u16* __restrict__ v, u16* __restrict__ vt){
  __shared__ u16 t[32][33];
  int bh = blockIdx.z;
  int t0 = blockIdx.x * 32, d0 = blockIdx.y * 32;
  int tx = threadIdx.x, ty = threadIdx.y;
  const u16* vs = v + (size_t)bh * T_ * D_;
  u16* vd = vt + (size_t)bh * T_ * D_;
  #pragma unroll
  for (int i = 0; i < 32; i += 8)
    t[ty + i][tx] = vs[(size_t)(t0 + ty + i) * D_ + d0 + tx];
  __syncthreads();
  #pragma unroll
  for (int i = 0; i < 32; i += 8)
    vd[(size_t)(d0 + ty + i) * T_ + t0 + tx] = t[tx][ty + i];
}

// ---------------- 128x128 GEMM, A[M][K] * Bt[N][K]^T, bf16 MFMA ----------------
template<int EPI>
__launch_bounds__(256, 2)
__global__ void k_gemm(const u16* __restrict__ A, const u16* __restrict__ Bt,
                       const float* __restrict__ bias, float* __restrict__ outF,
                       u16* __restrict__ oq, u16* __restrict__ ok, u16* __restrict__ ov,
                       int M, int N, int K){
  __shared__ u16 lA[128 * 32];
  __shared__ u16 lB[128 * 32];
  int tid = threadIdx.x, lane = tid & 63, wv = tid >> 6;
  int bm = blockIdx.y * 128, bn = blockIdx.x * 128;
  int wr = (wv >> 1) * 64, wc = (wv & 1) * 64;
  f32x4 acc[4][4] = {};

  const u16* Ab = A + (size_t)(bm + wv * 32 + (lane >> 2)) * K + (lane & 3) * 8;
  const u16* Bb = Bt + (size_t)(bn + wv * 32 + (lane >> 2)) * K + (lane & 3) * 8;
  u16* lAd = &lA[wv * 1024];
  u16* lBd = &lB[wv * 1024];
  int ar = wr + (lane & 15);
  int br = wc + (lane & 15);
  int kc = (lane >> 4) * 8;

  for (int k0 = 0; k0 < K; k0 += 32){
    gload_lds16(Ab + k0, lAd);
    gload_lds16(Ab + k0 + (size_t)16 * K, lAd + 512);
    gload_lds16(Bb + k0, lBd);
    gload_lds16(Bb + k0 + (size_t)16 * K, lBd + 512);
    __syncthreads();
    short8 afr[4], bfr[4];
    #pragma unroll
    for (int m = 0; m < 4; m++) afr[m] = *(const short8*)&lA[(ar + m * 16) * 32 + kc];
    #pragma unroll
    for (int n = 0; n < 4; n++) bfr[n] = *(const short8*)&lB[(br + n * 16) * 32 + kc];
    #pragma unroll
    for (int m = 0; m < 4; m++)
      #pragma unroll
      for (int n = 0; n < 4; n++)
        acc[m][n] = __builtin_amdgcn_mfma_f32_16x16x32_bf16(afr[m], bfr[n], acc[m][n], 0, 0, 0);
    __syncthreads();
  }

  if (EPI == 1){
    #pragma unroll
    for (int m = 0; m < 4; m++){
      int gmB = bm + wr + m * 16 + ((lane >> 4) << 2);
      #pragma unroll
      for (int n = 0; n < 4; n++){
        int gn = bn + wc + n * 16 + (lane & 15);
        float bia = bias[gn];
        #pragma unroll
        for (int j = 0; j < 4; j++)
          outF[(size_t)(gmB + j) * N + gn] = acc[m][n][j] + bia;
      }
    }
  } else {
    #pragma unroll
    for (int m = 0; m < 4; m++){
      int gmB = bm + wr + m * 16 + ((lane >> 4) << 2);
      #pragma unroll
      for (int n = 0; n < 4; n++){
        int gn = bn + wc + n * 16 + (lane & 15);
        float bia = bias[gn];
        int part = gn >> 10;
        int col = gn & 1023;
        int h = col >> 6, d = col & 63;
        u16* dst = (part == 0) ? oq : (part == 1) ? ok : ov;
        #pragma unroll
        for (int j = 0; j < 4; j++){
          int gm = gmB + j;
          int b = gm >> 11, t = gm & 2047;
          dst[((size_t)(b * H_ + h) * T_ + t) * D_ + d] = f2bf(acc[m][n][j] + bia);
        }
      }
    }
  }
}

// ---------------- flash attention (swapped-QK^T, lane-local softmax) ----------------
// q,k: [bh][T][D] bf16; vt: [bh][D][T] bf16; y: [b][t][C] bf16 (head-major cols)
// S^T = mfma(K,Q): lane holds q=lane&15, kv = n*16 + 4*(lane>>4) + r
// O^T = mfma(V^T,P^T): lane holds q=lane&15, d = n*16 + 4*(lane>>4) + r
__launch_bounds__(256, 2)
__global__ void k_attn(const u16* __restrict__ q, const u16* __restrict__ k,
                       const u16* __restrict__ vt, u16* __restrict__ y,
                       const float* __restrict__ tempPtr){
  __shared__ u16 lK[64 * 64];          // [kv][d], XOR-swizzled
  __shared__ u16 lV[64 * 64];          // [d][kv], XOR-swizzled
  __shared__ u16 lP[4][32 * 64];       // per-wave [q][kv], XOR-swizzled
  const float LOG2E = 1.44269504089f;
  int tid = threadIdx.x, lane = tid & 63, wv = tid >> 6;
  int g = lane >> 4, c = lane & 15;
  int bh = blockIdx.x, h = bh & (H_ - 1), b = bh >> 4;
  int yy = blockIdx.y;                 // longest q-tiles dispatched first
  int qt = (yy & 1) ? ((yy - 1) >> 1) : (15 - (yy >> 1));
  int q0 = qt * 128;
  int qb = q0 + wv * 32;
  float scl2 = LOG2E / (8.0f * tempPtr[0]);
  float slope2 = exp2f(-0.5f * (float)(h + 1)) * LOG2E;
  const u16* qp = q + (size_t)bh * T_ * D_;
  const u16* kp = k + (size_t)bh * T_ * D_;
  const u16* vp = vt + (size_t)bh * T_ * D_;
  char* lKc = (char*)lK;
  char* lVc = (char*)lV;
  char* lPw = (char*)lP[wv];

  // Q fragments (B-operand of S^T): lane holds Q[qb+m*16+c][ks*32+g*8 ..+7]
  short8 qf[2][2];
  #pragma unroll
  for (int m = 0; m < 2; m++)
    #pragma unroll
    for (int ks = 0; ks < 2; ks++)
      qf[m][ks] = *(const short8*)&qp[(size_t)(qb + m * 16 + c) * D_ + ks * 32 + g * 8];

  // per-lane ALiBi constants: bias = slope2*(kv - q) = slope2*kv0 + boff[i] - sq[m]
  float boff[16];
  #pragma unroll
  for (int n = 0; n < 4; n++)
    #pragma unroll
    for (int r = 0; r < 4; r++)
      boff[n * 4 + r] = slope2 * (float)(n * 16 + g * 4 + r);
  float sq[2] = { slope2 * (float)(qb + c), slope2 * (float)(qb + 16 + c) };

  float mrun[2] = { -1e30f, -1e30f }, lrun[2] = { 0.f, 0.f };
  f32x4 acco[2][4] = {};

  // staging: thread covers row sr, chunks sc*2 / sc*2+1 of both K and V tiles
  int sr = tid >> 2, sc = tid & 3;
  const u16* gK = kp + (size_t)sr * D_ + sc * 16;
  const u16* gV = vp + (size_t)sr * T_ + sc * 16;
  short8 rk0, rk1, rv0, rv1;

  int ntiles = (q0 >> 6) + 2;
  int wqmax = qb + 31;

  // prologue: issue tile-0 loads
  rk0 = *(const short8*)(gK);     rk1 = *(const short8*)(gK + 8);
  rv0 = *(const short8*)(gV);     rv1 = *(const short8*)(gV + 8);

  for (int t = 0; t < ntiles; t++){
    int kv0 = t << 6;
    __syncthreads();                         // all waves done reading prev tile
    *(short8*)(lKc + swzb(sr, sc * 2))     = rk0;
    *(short8*)(lKc + swzb(sr, sc * 2 + 1)) = rk1;
    *(short8*)(lVc + swzb(sr, sc * 2))     = rv0;
    *(short8*)(lVc + swzb(sr, sc * 2 + 1)) = rv1;
    __syncthreads();
    if (t + 1 < ntiles){                     // issue next-tile loads; latency hides under compute
      rk0 = *(const short8*)(gK + (t + 1) * 4096);
      rk1 = *(const short8*)(gK + (t + 1) * 4096 + 8);
      rv0 = *(const short8*)(gV + (t + 1) * 64);
      rv1 = *(const short8*)(gV + (t + 1) * 64 + 8);
    }
    if (kv0 > wqmax) continue;               // uniform per wave; barriers already done

    // ---- S^T = K * Q^T ----
    f32x4 accs[2][4] = {};
    #pragma unroll
    for (int ks = 0; ks < 2; ks++){
      short8 kf[4];
      #pragma unroll
      for (int n = 0; n < 4; n++)
        kf[n] = *(const short8*)(lKc + swzb(n * 16 + c, ks * 4 + g));
      #pragma unroll
      for (int m = 0; m < 2; m++)
        #pragma unroll
        for (int n = 0; n < 4; n++)
          accs[m][n] = __builtin_amdgcn_mfma_f32_16x16x32_bf16(kf[n], qf[m][ks], accs[m][n], 0, 0, 0);
    }

    bool maskt = (kv0 + 64 > qb);            // only the diagonal tile needs masking
    #pragma unroll
    for (int m = 0; m < 2; m++){
      float b0 = fmaf((float)kv0, slope2, -sq[m]);
      float s[16];
      #pragma unroll
      for (int n = 0; n < 4; n++)
        #pragma unroll
        for (int r = 0; r < 4; r++)
          s[n * 4 + r] = fmaf(accs[m][n][r], scl2, b0 + boff[n * 4 + r]);
      if (maskt){
        int qm = qb + m * 16 + c - kv0;
        #pragma unroll
        for (int n = 0; n < 4; n++)
          #pragma unroll
          for (int r = 0; r < 4; r++)
            s[n * 4 + r] = (n * 16 + g * 4 + r > qm) ? -1e30f : s[n * 4 + r];
      }
      float pm = s[0];
      #pragma unroll
      for (int i = 1; i < 16; i++) pm = fmaxf(pm, s[i]);
      pm = fmaxf(pm, __shfl_xor(pm, 16));
      pm = fmaxf(pm, __shfl_xor(pm, 32));
      if (!__all(pm <= mrun[m] + 8.0f)){     // defer-max: skip rescale on small growth
        float nm = fmaxf(mrun[m], pm);
        float al = exp2f(mrun[m] - nm);
        lrun[m] *= al;
        #pragma unroll
        for (int n = 0; n < 4; n++)
          #pragma unroll
          for (int r = 0; r < 4; r++)
            acco[m][n][r] *= al;
        mrun[m] = nm;
      }
      float p[16], ps = 0.f;
      #pragma unroll
      for (int i = 0; i < 16; i++){ p[i] = exp2f(s[i] - mrun[m]); ps += p[i]; }
      lrun[m] += ps;                         // per-lane partial; merged at the end
      #pragma unroll
      for (int n = 0; n < 4; n++){
        u32 w0 = ((u32)f2bf(p[n * 4 + 1]) << 16) | f2bf(p[n * 4 + 0]);
        u32 w1 = ((u32)f2bf(p[n * 4 + 3]) << 16) | f2bf(p[n * 4 + 2]);
        uint2 wp; wp.x = w0; wp.y = w1;
        *(uint2*)(lPw + swzb(c + 16 * m, 2 * n + (g >> 1)) + ((g & 1) << 3)) = wp;
      }
    }

    // ---- O^T += V^T * P^T ----
    #pragma unroll
    for (int ks = 0; ks < 2; ks++){
      short8 vf[4], pf[2];
      #pragma unroll
      for (int n = 0; n < 4; n++)
        vf[n] = *(const short8*)(lVc + swzb(n * 16 + c, ks * 4 + g));
      #pragma unroll
      for (int m = 0; m < 2; m++)
        pf[m] = *(const short8*)(lPw + swzb(c + 16 * m, ks * 4 + g));
      #pragma unroll
      for (int m = 0; m < 2; m++)
        #pragma unroll
        for (int n = 0; n < 4; n++)
          acco[m][n] = __builtin_amdgcn_mfma_f32_16x16x32_bf16(vf[n], pf[m], acco[m][n], 0, 0, 0);
    }
  }

  // epilogue: merge per-lane partial sums across the 4 groups, normalize, store
  #pragma unroll
  for (int m = 0; m < 2; m++){
    float ls = lrun[m];
    ls += __shfl_xor(ls, 16);
    ls += __shfl_xor(ls, 32);
    float inv = 1.0f / ls;
    int qg = qb + m * 16 + c;
    size_t rowoff = (size_t)(b * T_ + qg) * C_ + h * D_;
    #pragma unroll
    for (int n = 0; n < 4; n++){
      u32 w0 = ((u32)f2bf(acco[m][n][1] * inv) << 16) | f2bf(acco[m][n][0] * inv);
      u32 w1 = ((u32)f2bf(acco[m][n][3] * inv) << 16) | f2bf(acco[m][n][2] * inv);
      uint2 wp; wp.x = w0; wp.y = w1;
      *(uint2*)&y[rowoff + n * 16 + g * 4] = wp;
    }
  }
}

// ---------------- launcher ----------------
// Workspace layout (40 MB peak, aliased by lifetime):
//   [0,  8)  xb  -> vtw   [8,14) wab   [14,16) wpt
//   [16,24) qw   [24,32) kw   [32,40) vw -> yb
extern "C" void kernel_launch(void* const* d_in, const int* in_sizes, int n_in,
                              void* d_out, int out_size, void* d_ws, size_t ws_size,
                              hipStream_t stream){
  const float* x      = (const float*)d_in[0];
  const float* W_attn = (const float*)d_in[1];
  const float* b_attn = (const float*)d_in[2];
  const float* W_proj = (const float*)d_in[3];
  const float* b_proj = (const float*)d_in[4];
  const float* temp   = (const float*)d_in[5];
  float* out = (float*)d_out;

  if (ws_size < (size_t)41943040) return;  // need 40 MB scratch
  char* ws = (char*)d_ws;
  u16* xb  = (u16*)(ws);
  u16* wab = (u16*)(ws + 8388608);
  u16* wpt = (u16*)(ws + 14680064);
  u16* qw  = (u16*)(ws + 16777216);
  u16* kw  = (u16*)(ws + 25165824);
  u16* vw  = (u16*)(ws + 33554432);
  u16* vtw = (u16*)(ws);                    // overlays xb
  u16* yb  = (u16*)(ws + 33554432);         // overlays vw

  k_cvt_x<<<2048, 256, 0, stream>>>(x, xb);
  k_transW<<<dim3(96, 32), dim3(32, 8), 0, stream>>>(W_attn, wab, 1024, 3072);
  k_transW<<<dim3(32, 32), dim3(32, 8), 0, stream>>>(W_proj, wpt, 1024, 1024);
  k_gemm<0><<<dim3(24, 32), 256, 0, stream>>>(xb, wab, b_attn, nullptr, qw, kw, vw,
                                              4096, 3072, 1024);
  k_transV<<<dim3(64, 2, 32), dim3(32, 8), 0, stream>>>(vw, vtw);
  k_attn<<<dim3(32, 16), 256, 0, stream>>>(qw, kw, vtw, yb, temp);
  k_gemm<1><<<dim3(8, 32), 256, 0, stream>>>(yb, wpt, b_proj, out, nullptr, nullptr, nullptr,
                                             4096, 1024, 1024);
}